// Round 18
// baseline (43.534 us; speedup 1.0000x reference)
//
#include <hip/hip_runtime.h>

#define NQ    12
#define BATCH 8192

typedef float v2f __attribute__((ext_vector_type(2)));

// ---------------------------------------------------------------------------
// One wave simulates batch elements' 4096-dim real states (imag = 0),
// TWO elements sequentially per wave (theta setup amortized).
// Layout A: lane bits = qubits 6..11, reg bits = qubits 0..5
// Layout B: lane bits = qubits 0..5,  reg bits = qubits 6..11
// Per layer: 6 reg-gates, LDS transpose (2-phase pair-slot, S=66), 6 reg-
// gates, ring boundary CNOTs; sig-power renamings deferred at compile time.
// RY in tan form; G = prod cos folded into epilogue as G^2.
// c110A<0>/c110A<2> deferred into the next layerA (t0 sign flip + compile-
// time row-XOR base select in the A->B transpose read).
// ringB<3> folded into the epilogue sign bookkeeping (masks RM5=34 etc.).
// Theta trig + init trig vectorized (one sincos + readlane broadcasts).
// ---------------------------------------------------------------------------

constexpr int sig6(int x)            { return (x ^ (x << 1)) & 63; }
constexpr int sigpow6(int x, int t)  { return t == 0 ? x : sigpow6(sig6(x), t - 1); }
constexpr int rowmask6(int j, int t) {        // bit_j(sig^-t(p)) = par(p & m)
    int tt = (8 - (t % 8)) % 8;
    int m = 0;
    for (int i = 0; i < 6; ++i)
        if ((sigpow6(1 << i, tt) >> j) & 1) m |= 1 << i;
    return m;
}
constexpr bool par6(int x) { return (__builtin_popcount(x & 63) & 1) != 0; }

#define VAT(w, i) w[(i) >> 1][(i) & 1]

// ---- cross-lane helpers ---------------------------------------------------
template<int C>
__device__ __forceinline__ float dppf(float x) {
    return __int_as_float(__builtin_amdgcn_mov_dpp(__float_as_int(x), C, 0xF, 0xF, true));
}

template<int M>
__device__ __forceinline__ float shx(float x) {
    static_assert(M > 0 && M < 64, "mask");
    constexpr int lo = M & 31;
    float y = x;
    if constexpr (lo == 1)       y = dppf<0xB1>(y);
    else if constexpr (lo == 2)  y = dppf<0x4E>(y);
    else if constexpr (lo == 3)  y = dppf<0x1B>(y);
    else if constexpr (lo == 7)  y = dppf<0x141>(y);
    else if constexpr (lo == 15) y = dppf<0x140>(y);
    else if constexpr (lo != 0)
        y = __int_as_float(__builtin_amdgcn_ds_swizzle(__float_as_int(y),
                                                       0x1F | (lo << 10)));
    if constexpr ((M & 32) != 0) {
        int yi = __float_as_int(y);
        auto p = __builtin_amdgcn_permlane32_swap(yi, yi, false, false);
        y = (__int_as_float(p[0]) + __int_as_float(p[1])) - y;
    }
    return y;
}

// signed butterfly: value at lane L = (-1)^par(L&M) * sum_l (-1)^par(l&M) x_l
template<int M>
__device__ __forceinline__ float wave_red(float x) {
    { float o = dppf<0xB1>(x); x = (M & 1)  ? x - o : x + o; }
    { float o = dppf<0x4E>(x); x = (M & 2)  ? x - o : x + o; }
    { float o = __int_as_float(__builtin_amdgcn_ds_swizzle(__float_as_int(x), 0x1F | (4  << 10))); x = (M & 4)  ? x - o : x + o; }
    { float o = __int_as_float(__builtin_amdgcn_ds_swizzle(__float_as_int(x), 0x1F | (8  << 10))); x = (M & 8)  ? x - o : x + o; }
    { float o = __int_as_float(__builtin_amdgcn_ds_swizzle(__float_as_int(x), 0x1F | (16 << 10))); x = (M & 16) ? x - o : x + o; }
    int xi = __float_as_int(x);
    auto p = __builtin_amdgcn_permlane32_swap(xi, xi, false, false);
    float s = __int_as_float(p[0]) + __int_as_float(p[1]);
    return (M & 32) ? (2.0f * x - s) : s;
}

__device__ __forceinline__ float wave_prod(float x) {
    x *= dppf<0xB1>(x);
    x *= dppf<0x4E>(x);
    x *= __int_as_float(__builtin_amdgcn_ds_swizzle(__float_as_int(x), 0x1F | (4  << 10)));
    x *= __int_as_float(__builtin_amdgcn_ds_swizzle(__float_as_int(x), 0x1F | (8  << 10)));
    x *= __int_as_float(__builtin_amdgcn_ds_swizzle(__float_as_int(x), 0x1F | (16 << 10)));
    int xi = __float_as_int(x);
    auto p = __builtin_amdgcn_permlane32_swap(xi, xi, false, false);
    return __int_as_float(p[0]) * __int_as_float(p[1]);
}

__device__ __forceinline__ float rl(float v, int l) {
    return __int_as_float(__builtin_amdgcn_readlane(__float_as_int(v), l));
}

// ---- packed tan-form RY on reg qubit-bit Q, renaming sig^T ----------------
template<int T, int Q>
__device__ __forceinline__ void regRY(v2f* w, float t) {
    constexpr int D = sigpow6(1 << Q, T);   // physical partner xor
    const v2f tMM = {-t, -t}, tPP = {t, t}, tMP = {-t, t}, tPM = {t, -t};
    if constexpr (Q == 0) {
        constexpr int K = D >> 1;           // D odd: comp-swapped partner
        #pragma unroll
        for (int k = 0; k < 32; ++k) {
            const int k2 = k ^ K;
            if (k2 < k) continue;
            v2f a = w[k], b = w[k2];
            v2f sb = __builtin_shufflevector(b, b, 1, 0);
            v2f sa = __builtin_shufflevector(a, a, 1, 0);
            w[k]  = __builtin_elementwise_fma(tMP, sb, a);
            w[k2] = __builtin_elementwise_fma(tMP, sa, b);
        }
    } else {
        constexpr int K  = D >> 1;          // D even: comps aligned
        constexpr int RM = rowmask6(Q, T);
        #pragma unroll
        for (int k = 0; k < 32; ++k) {
            const int k2 = k ^ K;
            if (k2 < k) continue;
            const bool p = par6((2 * k) & RM);
            if constexpr (RM & 1) {
                v2f a = w[k], b = w[k2];
                const v2f tk  = p ? tPM : tMP;
                const v2f tk2 = p ? tMP : tPM;
                w[k]  = __builtin_elementwise_fma(tk,  b, a);
                w[k2] = __builtin_elementwise_fma(tk2, a, b);
            } else {
                if (p) {
                    v2f a = w[k2], b = w[k];
                    w[k2] = __builtin_elementwise_fma(tMM, b, a);
                    w[k]  = __builtin_elementwise_fma(tPP, a, b);
                } else {
                    v2f a = w[k], b = w[k2];
                    w[k]  = __builtin_elementwise_fma(tMM, b, a);
                    w[k2] = __builtin_elementwise_fma(tPP, a, b);
                }
            }
        }
    }
}

// ---- ring boundary CNOTs --------------------------------------------------
template<int T>          // layout A CNOT(5,6): reg bit5 controls lane xor
__device__ __forceinline__ void c56A(v2f* w) {
    constexpr int ML = sigpow6(1, T);
    #pragma unroll
    for (int r = 32; r < 64; ++r) {
        const int pr = sigpow6(r, T + 1);
        VAT(w, pr) = shx<ML>(VAT(w, pr));
    }
}
// (c110A is deferred -- see layerA's folded transpose)
template<int T>          // layout B CNOT(5,6): lane bit5 controls reg swap
__device__ __forceinline__ void c56B(v2f* w, int lane) {
    const bool cond = par6(lane & rowmask6(5, T + 1));
    constexpr int D = sigpow6(1, T);
    #pragma unroll
    for (int r0 = 0; r0 < 64; r0 += 2) {
        const int a0 = sigpow6(r0, T);
        const int a1 = a0 ^ D;
        float x0 = VAT(w, a0), x1 = VAT(w, a1);
        VAT(w, a0) = cond ? x1 : x0;
        VAT(w, a1) = cond ? x0 : x1;
    }
}
template<int T>          // layout B CNOT(11,0): reg bit5 controls lane xor
__device__ __forceinline__ void c110B(v2f* w) {
    constexpr int ML = sigpow6(1, T + 1);
    #pragma unroll
    for (int r = 32; r < 64; ++r) {
        const int pr = sigpow6(r, T + 1);
        VAT(w, pr) = shx<ML>(VAT(w, pr));
    }
}
template<int T>
__device__ __forceinline__ void ringB(v2f* w, int lane) { c56B<T>(w, lane); c110B<T>(w); }

// ---- lane<->reg transpose, 2-phase, pair-slot (S = 66), with optional fold -
template<int RM, int DX>
__device__ __forceinline__ void transpose64(v2f* w, float* sh, int lane) {
    const int row = lane & 31;
    const int rm0 = (lane >> 1) * 66 + (lane & 1);
    const int lx  = lane ^ DX;
    const int rm1 = (lx >> 1) * 66 + (lx & 1);   // used only when RM != 0
    v2f nv[16];
    if (lane < 32) {
        #pragma unroll
        for (int k = 0; k < 32; ++k)
            *reinterpret_cast<v2f*>(sh + row * 2 + k * 66) = w[k];
    }
    asm volatile("" ::: "memory");
    #pragma unroll
    for (int k = 0; k < 16; ++k) {               // old lanes rho = 2k, 2k+1
        if constexpr (RM == 0) {
            nv[k][0] = sh[rm0 + 4 * k];
            nv[k][1] = sh[rm0 + 4 * k + 2];
        } else {
            nv[k][0] = sh[(par6((2 * k)     & RM) ? rm1 : rm0) + 4 * k];
            nv[k][1] = sh[(par6((2 * k + 1) & RM) ? rm1 : rm0) + 4 * k + 2];
        }
    }
    asm volatile("" ::: "memory");
    if (lane >= 32) {
        #pragma unroll
        for (int k = 0; k < 32; ++k)
            *reinterpret_cast<v2f*>(sh + row * 2 + k * 66) = w[k];
    }
    asm volatile("" ::: "memory");
    #pragma unroll
    for (int k = 0; k < 16; ++k) {               // old lanes rho = 32+2k(+1)
        if constexpr (RM == 0) {
            w[16 + k][0] = sh[rm0 + 4 * k];
            w[16 + k][1] = sh[rm0 + 4 * k + 2];
        } else {
            w[16 + k][0] = sh[(par6((32 + 2 * k)     & RM) ? rm1 : rm0) + 4 * k];
            w[16 + k][1] = sh[(par6((32 + 2 * k + 1) & RM) ? rm1 : rm0) + 4 * k + 2];
        }
    }
    #pragma unroll
    for (int k = 0; k < 16; ++k) w[k] = nv[k];
    asm volatile("" ::: "memory");
}

// layer entering in layout A (theta row T; ends in layout B).
// RING=false: skip ringB<T> (folded into the epilogue -- final layer only).
template<int T, bool RING = true>
__device__ __forceinline__ void layerA(v2f* w, int lane, float* sh, float t_l) {
    constexpr int RMD = rowmask6(5, T);      // = rowmask6(5, (T-1)+1)
    constexpr int DXD = sigpow6(1, T);       // = sigpow6(1, (T-1)+1)
    const bool cnd = (__popc(lane & RMD) & 1) != 0;
    float t0 = rl(t_l, T * NQ + 0);
    regRY<T, 0>(w, cnd ? -t0 : t0);
    regRY<T, 1>(w, rl(t_l, T * NQ + 1));
    regRY<T, 2>(w, rl(t_l, T * NQ + 2));
    regRY<T, 3>(w, rl(t_l, T * NQ + 3));
    regRY<T, 4>(w, rl(t_l, T * NQ + 4));
    regRY<T, 5>(w, rl(t_l, T * NQ + 5));
    transpose64<RMD, DXD>(w, sh, lane);
    regRY<T, 0>(w, rl(t_l, T * NQ + 6));
    regRY<T, 1>(w, rl(t_l, T * NQ + 7));
    regRY<T, 2>(w, rl(t_l, T * NQ + 8));
    regRY<T, 3>(w, rl(t_l, T * NQ + 9));
    regRY<T, 4>(w, rl(t_l, T * NQ + 10));
    regRY<T, 5>(w, rl(t_l, T * NQ + 11));
    if constexpr (RING) ringB<T>(w, lane);
}

// layer entering in layout B (theta row T; ends in layout A)
template<int T>
__device__ __forceinline__ void layerB(v2f* w, int lane, float* sh, float t_l) {
    regRY<T, 0>(w, rl(t_l, T * NQ + 6));
    regRY<T, 1>(w, rl(t_l, T * NQ + 7));
    regRY<T, 2>(w, rl(t_l, T * NQ + 8));
    regRY<T, 3>(w, rl(t_l, T * NQ + 9));
    regRY<T, 4>(w, rl(t_l, T * NQ + 10));
    regRY<T, 5>(w, rl(t_l, T * NQ + 11));
    transpose64<0, 0>(w, sh, lane);
    regRY<T, 0>(w, rl(t_l, T * NQ + 0));
    regRY<T, 1>(w, rl(t_l, T * NQ + 1));
    regRY<T, 2>(w, rl(t_l, T * NQ + 2));
    regRY<T, 3>(w, rl(t_l, T * NQ + 3));
    regRY<T, 4>(w, rl(t_l, T * NQ + 4));
    regRY<T, 5>(w, rl(t_l, T * NQ + 5));
    c56A<T>(w);
    // c110A<T> deferred into the next layerA's gates + transpose
}

__global__ __launch_bounds__(256, 4)
void qc_kernel(const float* __restrict__ x, const float* __restrict__ theta,
               float* __restrict__ out) {
    __shared__ float shbuf[4][2112];   // max slot 31*66+63 = 2109, per wave
    const int lane = threadIdx.x & 63;
    const int wid  = threadIdx.x >> 6;
    const int base = __builtin_amdgcn_readfirstlane((blockIdx.x << 2) + wid);
    float* sh = &shbuf[wid][0];

    // ---- batch-invariant setup (hoisted out of the element loop):
    // lane q holds tan(theta[q]/2); G = prod cos over lanes 12..47.
    const float th_l = theta[lane < 48 ? lane : 0];
    float s5, c5;
    __sincosf(0.5f * th_l, &s5, &c5);
    const float t_l = s5 * __builtin_amdgcn_rcpf(c5);
    const float G = wave_prod((lane >= 12 && lane < 48) ? c5 : 1.0f);
    const float G2 = G * G;

    // ---- two batch elements per wave, sequentially
    #pragma unroll 1
    for (int e = 0; e < 2; ++e) {
        const int b = base + (e << 12);           // base, base + 4096

        // vectorized init trig: lane q<12: sincos(0.5*(x[b,q]+theta0[q]))
        const float xa = (lane < NQ) ? x[b * NQ + lane] : 0.0f;
        float sx, cx;
        __sincosf(0.5f * (xa + th_l), &sx, &cx);   // valid on lanes 0..11

        alignas(16) v2f w[32];

        // init in layout A (layer-0 thetas folded: RY(th)RY(x)|0> = RY(x+th)|0>)
        float L = 1.0f;
        #pragma unroll
        for (int q = 6; q < NQ; ++q)
            L *= ((lane >> (q - 6)) & 1) ? rl(sx, q) : rl(cx, q);
        w[0] = {L * rl(cx, 0), L * rl(sx, 0)};
        #pragma unroll
        for (int q = 1; q < 6; ++q) {
            const float s = rl(sx, q), c = rl(cx, q);
            const v2f vs = {s, s}, vc = {c, c};
            #pragma unroll
            for (int k = 0; k < (1 << (q - 1)); ++k) {
                w[k + (1 << (q - 1))] = w[k] * vs;
                w[k]                  = w[k] * vc;
            }
        }

        c56A<0>(w);                // layer-0 ring: c56A explicit, c110A<0> deferred
        layerA<1>(w, lane, sh, t_l);        // A -> B (materializes c110A<0>)
        layerB<2>(w, lane, sh, t_l);        // B -> A (c56A<2>; c110A<2> deferred)
        layerA<3, false>(w, lane, sh, t_l); // A -> B; ringB<3> folded into epilogue
        // final: layout B, renaming powers (4,4), missing perm M = C110 o C56'

        // epilogue: out[b,q] = G^2 * sum_e p[e] * sgn_q(M(e))
        #pragma unroll
        for (int k = 0; k < 32; ++k) w[k] = w[k] * w[k];

        v2f u1[16], c1[16];
        #pragma unroll
        for (int m = 0; m < 16; ++m) {
            u1[m] = w[2 * m] + w[2 * m + 1];
            c1[m] = w[2 * m] - w[2 * m + 1];     // sign: phys1
        }
        v2f u2[8], d2v = {0.f, 0.f};
        #pragma unroll
        for (int m = 0; m < 8; ++m) {
            u2[m] = u1[2 * m] + u1[2 * m + 1];
            d2v  += u1[2 * m] - u1[2 * m + 1];   // sign: phys2
        }
        v2f c2[8];
        #pragma unroll
        for (int m = 0; m < 8; ++m) c2[m] = c1[2 * m] + c1[2 * m + 1];
        v2f u3[4], d3v = {0.f, 0.f};
        #pragma unroll
        for (int m = 0; m < 4; ++m) {
            u3[m] = u2[2 * m] + u2[2 * m + 1];
            d3v  += u2[2 * m] - u2[2 * m + 1];   // sign: phys3
        }
        v2f c3[4];
        #pragma unroll
        for (int m = 0; m < 4; ++m) c3[m] = c2[2 * m] + c2[2 * m + 1];
        v2f u4[2], c4[2];
        u4[0] = u3[0] + u3[1]; u4[1] = u3[2] + u3[3];
        v2f d4v = (u3[0] - u3[1]) + (u3[2] - u3[3]);   // sign: phys4
        c4[0] = c3[0] + c3[1]; c4[1] = c3[2] + c3[3];
        v2f U  = u4[0] + u4[1];
        v2f cS = c4[0] + c4[1];                  // sign: phys1
        v2f cD = c4[0] - c4[1];                  // sign: phys1^phys5

        const float tot = U[0] + U[1];
        float Dq[6];                             // per-lane reg-weighted sums
        Dq[0] = U[0] - U[1];
        Dq[1] = cS[0] + cS[1];
        Dq[2] = d2v[0] + d2v[1];
        Dq[3] = d3v[0] + d3v[1];
        Dq[4] = d4v[0] - d4v[1];                 // ^phys0 via comp sign
        Dq[5] = cD[0] + cD[1];

        constexpr int RM5 = rowmask6(5, 4);      // lane parity mask, qubit 5 (=34)
        float res[NQ];
        res[0] = wave_red<rowmask6(0, 4) ^ RM5>(Dq[5]);
        res[1] = wave_red<rowmask6(1, 4)>(tot);
        res[2] = wave_red<rowmask6(2, 4)>(tot);
        res[3] = wave_red<rowmask6(3, 4)>(tot);
        res[4] = wave_red<rowmask6(4, 4)>(tot);
        res[5] = wave_red<rowmask6(5, 4)>(tot);
        #pragma unroll
        for (int j = 0; j < 6; ++j) {
            const float v = wave_red<RM5>(Dq[j]);
            res[6 + j] = par6((6 + j) & RM5) ? -v : v;
        }

        float myres = res[0];
        #pragma unroll
        for (int q = 1; q < NQ; ++q) myres = (lane == q) ? res[q] : myres;
        myres *= G2;
        if (lane < NQ) out[b * NQ + lane] = myres;
    }
}

extern "C" void kernel_launch(void* const* d_in, const int* in_sizes, int n_in,
                              void* d_out, int out_size, void* d_ws, size_t ws_size,
                              hipStream_t stream) {
    const float* x     = (const float*)d_in[0];
    const float* theta = (const float*)d_in[1];
    float* out = (float*)d_out;
    dim3 grid(BATCH / 8), block(256);
    qc_kernel<<<grid, block, 0, stream>>>(x, theta, out);
}

// Round 19
// 41.393 us; speedup vs baseline: 1.0517x; 1.0517x over previous
//
#include <hip/hip_runtime.h>

#define NQ    12
#define BATCH 8192

typedef float v2f __attribute__((ext_vector_type(2)));

// ---------------------------------------------------------------------------
// One wave = one batch element's 4096-dim real state (imag identically 0).
// Layout A: lane bits = qubits 6..11, reg bits = qubits 0..5
// Layout B: lane bits = qubits 0..5,  reg bits = qubits 6..11
// Per layer: 6 reg-gates, LDS transpose (2-phase pair-slot, S=66), 6 reg-
// gates, ring boundary CNOTs; sig-power renamings deferred at compile time.
// RY in tan form; G = prod cos folded into epilogue as G^2.
// Gates via __builtin_elementwise_fma -> v_pk_fma_f32 (compiler op_sel).
// c110A<0>/c110A<2> deferred into the next layerA (t0 sign flip + compile-
// time row-XOR base select in the A->B transpose read).
// ringB<3> folded into the epilogue sign bookkeeping (masks RM5=34 etc.).
// Theta trig + init trig vectorized (one sincos + readlane broadcasts).
// This round: revert to the R17 configuration (best measured: 41.4 us).
// ---------------------------------------------------------------------------

constexpr int sig6(int x)            { return (x ^ (x << 1)) & 63; }
constexpr int sigpow6(int x, int t)  { return t == 0 ? x : sigpow6(sig6(x), t - 1); }
constexpr int rowmask6(int j, int t) {        // bit_j(sig^-t(p)) = par(p & m)
    int tt = (8 - (t % 8)) % 8;
    int m = 0;
    for (int i = 0; i < 6; ++i)
        if ((sigpow6(1 << i, tt) >> j) & 1) m |= 1 << i;
    return m;
}
constexpr bool par6(int x) { return (__builtin_popcount(x & 63) & 1) != 0; }

#define VAT(w, i) w[(i) >> 1][(i) & 1]

// ---- cross-lane helpers ---------------------------------------------------
template<int C>
__device__ __forceinline__ float dppf(float x) {
    return __int_as_float(__builtin_amdgcn_mov_dpp(__float_as_int(x), C, 0xF, 0xF, true));
}

template<int M>
__device__ __forceinline__ float shx(float x) {
    static_assert(M > 0 && M < 64, "mask");
    constexpr int lo = M & 31;
    float y = x;
    if constexpr (lo == 1)       y = dppf<0xB1>(y);
    else if constexpr (lo == 2)  y = dppf<0x4E>(y);
    else if constexpr (lo == 3)  y = dppf<0x1B>(y);
    else if constexpr (lo == 7)  y = dppf<0x141>(y);
    else if constexpr (lo == 15) y = dppf<0x140>(y);
    else if constexpr (lo != 0)
        y = __int_as_float(__builtin_amdgcn_ds_swizzle(__float_as_int(y),
                                                       0x1F | (lo << 10)));
    if constexpr ((M & 32) != 0) {
        int yi = __float_as_int(y);
        auto p = __builtin_amdgcn_permlane32_swap(yi, yi, false, false);
        y = (__int_as_float(p[0]) + __int_as_float(p[1])) - y;
    }
    return y;
}

// signed butterfly: value at lane L = (-1)^par(L&M) * sum_l (-1)^par(l&M) x_l
template<int M>
__device__ __forceinline__ float wave_red(float x) {
    { float o = dppf<0xB1>(x); x = (M & 1)  ? x - o : x + o; }
    { float o = dppf<0x4E>(x); x = (M & 2)  ? x - o : x + o; }
    { float o = __int_as_float(__builtin_amdgcn_ds_swizzle(__float_as_int(x), 0x1F | (4  << 10))); x = (M & 4)  ? x - o : x + o; }
    { float o = __int_as_float(__builtin_amdgcn_ds_swizzle(__float_as_int(x), 0x1F | (8  << 10))); x = (M & 8)  ? x - o : x + o; }
    { float o = __int_as_float(__builtin_amdgcn_ds_swizzle(__float_as_int(x), 0x1F | (16 << 10))); x = (M & 16) ? x - o : x + o; }
    int xi = __float_as_int(x);
    auto p = __builtin_amdgcn_permlane32_swap(xi, xi, false, false);
    float s = __int_as_float(p[0]) + __int_as_float(p[1]);
    return (M & 32) ? (2.0f * x - s) : s;
}

__device__ __forceinline__ float wave_prod(float x) {
    x *= dppf<0xB1>(x);
    x *= dppf<0x4E>(x);
    x *= __int_as_float(__builtin_amdgcn_ds_swizzle(__float_as_int(x), 0x1F | (4  << 10)));
    x *= __int_as_float(__builtin_amdgcn_ds_swizzle(__float_as_int(x), 0x1F | (8  << 10)));
    x *= __int_as_float(__builtin_amdgcn_ds_swizzle(__float_as_int(x), 0x1F | (16 << 10)));
    int xi = __float_as_int(x);
    auto p = __builtin_amdgcn_permlane32_swap(xi, xi, false, false);
    return __int_as_float(p[0]) * __int_as_float(p[1]);
}

__device__ __forceinline__ float rl(float v, int l) {
    return __int_as_float(__builtin_amdgcn_readlane(__float_as_int(v), l));
}

// ---- packed tan-form RY on reg qubit-bit Q, renaming sig^T ----------------
template<int T, int Q>
__device__ __forceinline__ void regRY(v2f* w, float t) {
    constexpr int D = sigpow6(1 << Q, T);   // physical partner xor
    const v2f tMM = {-t, -t}, tPP = {t, t}, tMP = {-t, t}, tPM = {t, -t};
    if constexpr (Q == 0) {
        constexpr int K = D >> 1;           // D odd: comp-swapped partner
        #pragma unroll
        for (int k = 0; k < 32; ++k) {
            const int k2 = k ^ K;
            if (k2 < k) continue;
            v2f a = w[k], b = w[k2];
            v2f sb = __builtin_shufflevector(b, b, 1, 0);
            v2f sa = __builtin_shufflevector(a, a, 1, 0);
            w[k]  = __builtin_elementwise_fma(tMP, sb, a);
            w[k2] = __builtin_elementwise_fma(tMP, sa, b);
        }
    } else {
        constexpr int K  = D >> 1;          // D even: comps aligned
        constexpr int RM = rowmask6(Q, T);
        #pragma unroll
        for (int k = 0; k < 32; ++k) {
            const int k2 = k ^ K;
            if (k2 < k) continue;
            const bool p = par6((2 * k) & RM);
            if constexpr (RM & 1) {
                v2f a = w[k], b = w[k2];
                const v2f tk  = p ? tPM : tMP;
                const v2f tk2 = p ? tMP : tPM;
                w[k]  = __builtin_elementwise_fma(tk,  b, a);
                w[k2] = __builtin_elementwise_fma(tk2, a, b);
            } else {
                if (p) {
                    v2f a = w[k2], b = w[k];
                    w[k2] = __builtin_elementwise_fma(tMM, b, a);
                    w[k]  = __builtin_elementwise_fma(tPP, a, b);
                } else {
                    v2f a = w[k], b = w[k2];
                    w[k]  = __builtin_elementwise_fma(tMM, b, a);
                    w[k2] = __builtin_elementwise_fma(tPP, a, b);
                }
            }
        }
    }
}

// ---- ring boundary CNOTs --------------------------------------------------
template<int T>          // layout A CNOT(5,6): reg bit5 controls lane xor
__device__ __forceinline__ void c56A(v2f* w) {
    constexpr int ML = sigpow6(1, T);
    #pragma unroll
    for (int r = 32; r < 64; ++r) {
        const int pr = sigpow6(r, T + 1);
        VAT(w, pr) = shx<ML>(VAT(w, pr));
    }
}
// (c110A is deferred -- see layerA's folded transpose)
template<int T>          // layout B CNOT(5,6): lane bit5 controls reg swap
__device__ __forceinline__ void c56B(v2f* w, int lane) {
    const bool cond = par6(lane & rowmask6(5, T + 1));
    constexpr int D = sigpow6(1, T);
    #pragma unroll
    for (int r0 = 0; r0 < 64; r0 += 2) {
        const int a0 = sigpow6(r0, T);
        const int a1 = a0 ^ D;
        float x0 = VAT(w, a0), x1 = VAT(w, a1);
        VAT(w, a0) = cond ? x1 : x0;
        VAT(w, a1) = cond ? x0 : x1;
    }
}
template<int T>          // layout B CNOT(11,0): reg bit5 controls lane xor
__device__ __forceinline__ void c110B(v2f* w) {
    constexpr int ML = sigpow6(1, T + 1);
    #pragma unroll
    for (int r = 32; r < 64; ++r) {
        const int pr = sigpow6(r, T + 1);
        VAT(w, pr) = shx<ML>(VAT(w, pr));
    }
}
template<int T>
__device__ __forceinline__ void ringB(v2f* w, int lane) { c56B<T>(w, lane); c110B<T>(w); }

// ---- lane<->reg transpose, 2-phase, pair-slot (S = 66), with optional fold -
template<int RM, int DX>
__device__ __forceinline__ void transpose64(v2f* w, float* sh, int lane) {
    const int row = lane & 31;
    const int rm0 = (lane >> 1) * 66 + (lane & 1);
    const int lx  = lane ^ DX;
    const int rm1 = (lx >> 1) * 66 + (lx & 1);   // used only when RM != 0
    v2f nv[16];
    if (lane < 32) {
        #pragma unroll
        for (int k = 0; k < 32; ++k)
            *reinterpret_cast<v2f*>(sh + row * 2 + k * 66) = w[k];
    }
    asm volatile("" ::: "memory");
    #pragma unroll
    for (int k = 0; k < 16; ++k) {               // old lanes rho = 2k, 2k+1
        if constexpr (RM == 0) {
            nv[k][0] = sh[rm0 + 4 * k];
            nv[k][1] = sh[rm0 + 4 * k + 2];
        } else {
            nv[k][0] = sh[(par6((2 * k)     & RM) ? rm1 : rm0) + 4 * k];
            nv[k][1] = sh[(par6((2 * k + 1) & RM) ? rm1 : rm0) + 4 * k + 2];
        }
    }
    asm volatile("" ::: "memory");
    if (lane >= 32) {
        #pragma unroll
        for (int k = 0; k < 32; ++k)
            *reinterpret_cast<v2f*>(sh + row * 2 + k * 66) = w[k];
    }
    asm volatile("" ::: "memory");
    #pragma unroll
    for (int k = 0; k < 16; ++k) {               // old lanes rho = 32+2k(+1)
        if constexpr (RM == 0) {
            w[16 + k][0] = sh[rm0 + 4 * k];
            w[16 + k][1] = sh[rm0 + 4 * k + 2];
        } else {
            w[16 + k][0] = sh[(par6((32 + 2 * k)     & RM) ? rm1 : rm0) + 4 * k];
            w[16 + k][1] = sh[(par6((32 + 2 * k + 1) & RM) ? rm1 : rm0) + 4 * k + 2];
        }
    }
    #pragma unroll
    for (int k = 0; k < 16; ++k) w[k] = nv[k];
    asm volatile("" ::: "memory");
}

// layer entering in layout A (theta row T; ends in layout B).
// RING=false: skip ringB<T> (folded into the epilogue -- final layer only).
template<int T, bool RING = true>
__device__ __forceinline__ void layerA(v2f* w, int lane, float* sh, float t_l) {
    constexpr int RMD = rowmask6(5, T);      // = rowmask6(5, (T-1)+1)
    constexpr int DXD = sigpow6(1, T);       // = sigpow6(1, (T-1)+1)
    const bool cnd = (__popc(lane & RMD) & 1) != 0;
    float t0 = rl(t_l, T * NQ + 0);
    regRY<T, 0>(w, cnd ? -t0 : t0);
    regRY<T, 1>(w, rl(t_l, T * NQ + 1));
    regRY<T, 2>(w, rl(t_l, T * NQ + 2));
    regRY<T, 3>(w, rl(t_l, T * NQ + 3));
    regRY<T, 4>(w, rl(t_l, T * NQ + 4));
    regRY<T, 5>(w, rl(t_l, T * NQ + 5));
    transpose64<RMD, DXD>(w, sh, lane);
    regRY<T, 0>(w, rl(t_l, T * NQ + 6));
    regRY<T, 1>(w, rl(t_l, T * NQ + 7));
    regRY<T, 2>(w, rl(t_l, T * NQ + 8));
    regRY<T, 3>(w, rl(t_l, T * NQ + 9));
    regRY<T, 4>(w, rl(t_l, T * NQ + 10));
    regRY<T, 5>(w, rl(t_l, T * NQ + 11));
    if constexpr (RING) ringB<T>(w, lane);
}

// layer entering in layout B (theta row T; ends in layout A)
template<int T>
__device__ __forceinline__ void layerB(v2f* w, int lane, float* sh, float t_l) {
    regRY<T, 0>(w, rl(t_l, T * NQ + 6));
    regRY<T, 1>(w, rl(t_l, T * NQ + 7));
    regRY<T, 2>(w, rl(t_l, T * NQ + 8));
    regRY<T, 3>(w, rl(t_l, T * NQ + 9));
    regRY<T, 4>(w, rl(t_l, T * NQ + 10));
    regRY<T, 5>(w, rl(t_l, T * NQ + 11));
    transpose64<0, 0>(w, sh, lane);
    regRY<T, 0>(w, rl(t_l, T * NQ + 0));
    regRY<T, 1>(w, rl(t_l, T * NQ + 1));
    regRY<T, 2>(w, rl(t_l, T * NQ + 2));
    regRY<T, 3>(w, rl(t_l, T * NQ + 3));
    regRY<T, 4>(w, rl(t_l, T * NQ + 4));
    regRY<T, 5>(w, rl(t_l, T * NQ + 5));
    c56A<T>(w);
    // c110A<T> deferred into the next layerA's gates + transpose
}

__global__ __launch_bounds__(256, 4)
void qc_kernel(const float* __restrict__ x, const float* __restrict__ theta,
               float* __restrict__ out) {
    __shared__ float shbuf[4][2112];   // max slot 31*66+63 = 2109, per wave
    const int lane = threadIdx.x & 63;
    const int wid  = threadIdx.x >> 6;
    const int b = __builtin_amdgcn_readfirstlane((blockIdx.x << 2) + wid);
    float* sh = &shbuf[wid][0];

    // ---- vectorized theta trig: lane q holds tan(theta[q]/2); G = prod cos
    // over lanes 12..47 (layers 1..3; layer 0 folded into init).
    const float th_l = theta[lane < 48 ? lane : 0];
    float s5, c5;
    __sincosf(0.5f * th_l, &s5, &c5);
    const float t_l = s5 * __builtin_amdgcn_rcpf(c5);
    const float G = wave_prod((lane >= 12 && lane < 48) ? c5 : 1.0f);

    // ---- vectorized init trig: lane q<12 computes sincos(0.5*(x[b,q]+th0[q]))
    const float xa = (lane < NQ) ? x[b * NQ + lane] : 0.0f;
    float sx, cx;
    __sincosf(0.5f * (xa + th_l), &sx, &cx);   // valid on lanes 0..11

    alignas(16) v2f w[32];

    // ---- init in layout A (layer-0 thetas folded: RY(th)RY(x)|0> = RY(x+th)|0>)
    float L = 1.0f;
    #pragma unroll
    for (int q = 6; q < NQ; ++q)
        L *= ((lane >> (q - 6)) & 1) ? rl(sx, q) : rl(cx, q);
    w[0] = {L * rl(cx, 0), L * rl(sx, 0)};
    #pragma unroll
    for (int q = 1; q < 6; ++q) {
        const float s = rl(sx, q), c = rl(cx, q);
        const v2f vs = {s, s}, vc = {c, c};
        #pragma unroll
        for (int k = 0; k < (1 << (q - 1)); ++k) {
            w[k + (1 << (q - 1))] = w[k] * vs;
            w[k]                  = w[k] * vc;
        }
    }

    c56A<0>(w);                // layer-0 ring: c56A explicit, c110A<0> deferred
    layerA<1>(w, lane, sh, t_l);        // A -> B (materializes c110A<0>)
    layerB<2>(w, lane, sh, t_l);        // B -> A (c56A<2>; c110A<2> deferred)
    layerA<3, false>(w, lane, sh, t_l); // A -> B; ringB<3> FOLDED into epilogue
    // final: layout B, renaming powers (4,4), missing perm M = C110 o C56'

    // ---- epilogue: out[b,q] = G^2 * sum_e p[e] * sgn_q(M(e))
    // phys = sig^4(L): comp = phys bit0; w-index bits = phys bits 1..5.
    #pragma unroll
    for (int k = 0; k < 32; ++k) w[k] = w[k] * w[k];

    v2f u1[16], c1[16];
    #pragma unroll
    for (int m = 0; m < 16; ++m) {
        u1[m] = w[2 * m] + w[2 * m + 1];
        c1[m] = w[2 * m] - w[2 * m + 1];     // sign: phys1
    }
    v2f u2[8], d2v = {0.f, 0.f};
    #pragma unroll
    for (int m = 0; m < 8; ++m) {
        u2[m] = u1[2 * m] + u1[2 * m + 1];
        d2v  += u1[2 * m] - u1[2 * m + 1];   // sign: phys2
    }
    v2f c2[8];
    #pragma unroll
    for (int m = 0; m < 8; ++m) c2[m] = c1[2 * m] + c1[2 * m + 1];
    v2f u3[4], d3v = {0.f, 0.f};
    #pragma unroll
    for (int m = 0; m < 4; ++m) {
        u3[m] = u2[2 * m] + u2[2 * m + 1];
        d3v  += u2[2 * m] - u2[2 * m + 1];   // sign: phys3
    }
    v2f c3[4];
    #pragma unroll
    for (int m = 0; m < 4; ++m) c3[m] = c2[2 * m] + c2[2 * m + 1];
    v2f u4[2], c4[2];
    u4[0] = u3[0] + u3[1]; u4[1] = u3[2] + u3[3];
    v2f d4v = (u3[0] - u3[1]) + (u3[2] - u3[3]);   // sign: phys4
    c4[0] = c3[0] + c3[1]; c4[1] = c3[2] + c3[3];
    v2f U  = u4[0] + u4[1];
    v2f cS = c4[0] + c4[1];                  // sign: phys1
    v2f cD = c4[0] - c4[1];                  // sign: phys1^phys5

    const float tot = U[0] + U[1];
    float Dq[6];                             // per-lane: sum_r v^2 (-1)^bit(6+j)
    Dq[0] = U[0] - U[1];
    Dq[1] = cS[0] + cS[1];
    Dq[2] = d2v[0] + d2v[1];
    Dq[3] = d3v[0] + d3v[1];
    Dq[4] = d4v[0] - d4v[1];                 // ^phys0 via comp sign
    Dq[5] = cD[0] + cD[1];

    constexpr int RM5 = rowmask6(5, 4);      // lane parity mask for qubit 5 (=34)
    float res[NQ];
    // q=0: sgn = (-1)^(q0 ^ q11 ^ q5): lane mask rowmask6(0,4)^RM5, reg wt Dq[5]
    res[0] = wave_red<rowmask6(0, 4) ^ RM5>(Dq[5]);
    res[1] = wave_red<rowmask6(1, 4)>(tot);  // lane qubits 1..5 unchanged
    res[2] = wave_red<rowmask6(2, 4)>(tot);
    res[3] = wave_red<rowmask6(3, 4)>(tot);
    res[4] = wave_red<rowmask6(4, 4)>(tot);
    res[5] = wave_red<rowmask6(5, 4)>(tot);
    // q=6..11: sgn gains (-1)^q5 -> wave_red mask RM5; fix writing-lane sign
    #pragma unroll
    for (int j = 0; j < 6; ++j) {
        const float v = wave_red<RM5>(Dq[j]);
        res[6 + j] = par6((6 + j) & RM5) ? -v : v;
    }

    float myres = res[0];
    #pragma unroll
    for (int q = 1; q < NQ; ++q) myres = (lane == q) ? res[q] : myres;
    myres *= G * G;
    if (lane < NQ) out[b * NQ + lane] = myres;
}

extern "C" void kernel_launch(void* const* d_in, const int* in_sizes, int n_in,
                              void* d_out, int out_size, void* d_ws, size_t ws_size,
                              hipStream_t stream) {
    const float* x     = (const float*)d_in[0];
    const float* theta = (const float*)d_in[1];
    float* out = (float*)d_out;
    dim3 grid(BATCH / 4), block(256);
    qc_kernel<<<grid, block, 0, stream>>>(x, theta, out);
}